// Round 1
// baseline (395.714 us; speedup 1.0000x reference)
//
#include <hip/hip_runtime.h>
#include <math.h>

typedef __attribute__((ext_vector_type(4))) float f32x4;
typedef __attribute__((ext_vector_type(8))) __bf16 bf16x8;
typedef __attribute__((ext_vector_type(4))) unsigned int u32x4;
typedef __attribute__((ext_vector_type(2))) unsigned int u32x2;
typedef __attribute__((ext_vector_type(4))) unsigned short u16x4;

#define DEVI __device__ __forceinline__

// B=4, S=2048, E=1024, H=16, D=64, M=B*S=8192
// ws layout (bytes):
//   Wb   : 4 x 1M bf16 weights              @ 0        (8 MB)
//   cosT : 2048*32 f32                       @ 8 MB     (256 KB)
//   sinT : 2048*32 f32                       @ 8.25 MB  (256 KB)
//   Qh   : [64 bh][2048 s][64 d] bf16        @ 8.5 MB   (16 MB)
//   Kh   : same                              @ 24.5 MB
//   Vt   : [64 bh][64 d][2048 s] bf16        @ 40.5 MB
//   AO   : [8192][1024] f32 attn output      @ 56.5 MB  (32 MB)  -> need 88.5 MB ws
constexpr size_t WS_WB  = 0;
constexpr size_t WS_COS = 4ull * 1024 * 1024 * 2;
constexpr size_t WS_SIN = WS_COS + 2048 * 32 * 4;
constexpr size_t WS_QH  = WS_SIN + 2048 * 32 * 4;
constexpr size_t WS_KH  = WS_QH + 64ull * 2048 * 64 * 2;
constexpr size_t WS_VT  = WS_KH + 64ull * 2048 * 64 * 2;
constexpr size_t WS_AO  = WS_VT + 64ull * 64 * 2048 * 2;

DEVI unsigned short f2bf(float x) {
  union { float f; unsigned int u; } v; v.f = x;
  unsigned int r = v.u + 0x7fffu + ((v.u >> 16) & 1u);  // RNE
  return (unsigned short)(r >> 16);
}

// ---------------- weights fp32 -> bf16 ----------------
__global__ __launch_bounds__(256) void cvt_w(const float* __restrict__ w0,
                                             const float* __restrict__ w1,
                                             const float* __restrict__ w2,
                                             const float* __restrict__ w3,
                                             unsigned short* __restrict__ out) {
  const float* w = blockIdx.y == 0 ? w0 : blockIdx.y == 1 ? w1 : blockIdx.y == 2 ? w2 : w3;
  int i = (blockIdx.x * 256 + threadIdx.x) * 4;
  f32x4 v = *(const f32x4*)(w + i);
  u16x4 o;
  o.x = f2bf(v.x); o.y = f2bf(v.y); o.z = f2bf(v.z); o.w = f2bf(v.w);
  *(u16x4*)(out + (size_t)blockIdx.y * 1048576 + i) = o;
}

// ---------------- RoPE tables (f64 for angle precision) ----------------
__global__ __launch_bounds__(256) void rope_tab(float* __restrict__ cosT,
                                                float* __restrict__ sinT) {
  int idx = blockIdx.x * 256 + threadIdx.x;  // 65536 = 2048*32
  int s = idx >> 5, i = idx & 31;
  double ang = (double)s * pow(10000.0, -(double)i / 32.0);
  cosT[idx] = (float)cos(ang);
  sinT[idx] = (float)sin(ang);
}

// ---------------- 128x128x(K=1024) GEMM, A fp32 row-major, W bf16 [n][k] ----------------
// C[m][n] = sum_k A[m][k]*W[n][k].  EPI: 0=Q(rope,scale), 1=K(rope), 2=V(transposed store), 3=out(f32+bias)
template <int EPI>
__global__ __launch_bounds__(256) void gemm_mha(const float* __restrict__ A,
                                                const unsigned short* __restrict__ W,
                                                void* __restrict__ outp,
                                                const float* __restrict__ cosT,
                                                const float* __restrict__ sinT,
                                                const float* __restrict__ bo) {
  __shared__ unsigned short As[128 * 40];  // 32 bf16 data + 8 pad per row (80B rows: 2-way banks max)
  __shared__ unsigned short Bs[128 * 40];
  const int tid = threadIdx.x;
  const int lane = tid & 63;
  const int wave = tid >> 6;
  const int n0 = blockIdx.x * 128;
  const int m0 = blockIdx.y * 128;
  const int wm = (wave >> 1) * 64;
  const int wn = (wave & 1) * 64;

  f32x4 acc[4][4] = {};

  const int aRow = tid >> 3;  // 0..31
  const int aU = tid & 7;     // float4 unit within 32-float row

  for (int kt = 0; kt < 32; ++kt) {
    const int k0 = kt * 32;
    f32x4 av[4];
#pragma unroll
    for (int i = 0; i < 4; ++i)
      av[i] = *(const f32x4*)(A + (size_t)(m0 + aRow + 32 * i) * 1024 + k0 + aU * 4);
    u32x4 wv[2];
#pragma unroll
    for (int j = 0; j < 2; ++j) {
      int r = wave * 32 + j * 16 + (lane >> 2);
      wv[j] = *(const u32x4*)(W + (size_t)(n0 + r) * 1024 + k0 + (lane & 3) * 8);
    }
    __syncthreads();  // prior iter's LDS reads done
#pragma unroll
    for (int i = 0; i < 4; ++i) {
      int r = aRow + 32 * i;
      u32x2 p;
      p.x = (unsigned)f2bf(av[i].x) | ((unsigned)f2bf(av[i].y) << 16);
      p.y = (unsigned)f2bf(av[i].z) | ((unsigned)f2bf(av[i].w) << 16);
      *(u32x2*)(As + r * 40 + aU * 4) = p;
    }
#pragma unroll
    for (int j = 0; j < 2; ++j) {
      int r = wave * 32 + j * 16 + (lane >> 2);
      *(u32x4*)(Bs + r * 40 + (lane & 3) * 8) = wv[j];
    }
    __syncthreads();
    bf16x8 af[4], bfr[4];
#pragma unroll
    for (int x = 0; x < 4; ++x) {
      af[x] = *(const bf16x8*)(As + (wm + x * 16 + (lane & 15)) * 40 + (lane >> 4) * 8);
      bfr[x] = *(const bf16x8*)(Bs + (wn + x * 16 + (lane & 15)) * 40 + (lane >> 4) * 8);
    }
#pragma unroll
    for (int mi = 0; mi < 4; ++mi)
#pragma unroll
      for (int ni = 0; ni < 4; ++ni)
        acc[mi][ni] = __builtin_amdgcn_mfma_f32_16x16x32_bf16(af[mi], bfr[ni], acc[mi][ni], 0, 0, 0);
  }

  // -------- epilogue --------
  const int b = m0 >> 11;                                   // tile never crosses batch boundary
  const int sbase = (m0 & 2047) + wm + ((lane >> 4) << 2);  // + mi*16 + r

  if constexpr (EPI == 0 || EPI == 1) {
    unsigned short* dst = (unsigned short*)outp;
#pragma unroll
    for (int ni = 0; ni < 4; ++ni) {
      int n = n0 + wn + ni * 16 + (lane & 15);
      int h = n >> 6, d = n & 63, fi = d >> 1;
      size_t base = (size_t)(b * 16 + h) * 131072 + d;  // bh*2048*64 + d
#pragma unroll
      for (int mi = 0; mi < 4; ++mi) {
#pragma unroll
        for (int r = 0; r < 4; ++r) {
          int s = sbase + mi * 16 + r;
          float v = acc[mi][ni][r];
          float p = __shfl_xor(v, 1);  // partner element of the rope pair (d^1)
          float c = cosT[(s << 5) + fi], sn = sinT[(s << 5) + fi];
          float ov = (d & 1) ? (p * sn + v * c) : (v * c - p * sn);
          if (EPI == 0) ov *= 0.125f;  // 1/sqrt(64) folded into Q
          dst[base + (size_t)s * 64] = f2bf(ov);
        }
      }
    }
  } else if constexpr (EPI == 2) {
    unsigned short* dst = (unsigned short*)outp;  // Vt [bh][d][s]
#pragma unroll
    for (int ni = 0; ni < 4; ++ni) {
      int n = n0 + wn + ni * 16 + (lane & 15);
      int h = n >> 6, d = n & 63;
#pragma unroll
      for (int mi = 0; mi < 4; ++mi) {
        u16x4 pk;
        pk.x = f2bf(acc[mi][ni][0]); pk.y = f2bf(acc[mi][ni][1]);
        pk.z = f2bf(acc[mi][ni][2]); pk.w = f2bf(acc[mi][ni][3]);
        int s = sbase + mi * 16;  // 4 consecutive s (regs) -> 8B store
        *(u16x4*)(dst + ((size_t)(b * 16 + h) * 64 + d) * 2048 + s) = pk;
      }
    }
  } else {
    float* dst = (float*)outp;
#pragma unroll
    for (int ni = 0; ni < 4; ++ni) {
      int n = n0 + wn + ni * 16 + (lane & 15);
      float bias = bo[n];
#pragma unroll
      for (int mi = 0; mi < 4; ++mi)
#pragma unroll
        for (int r = 0; r < 4; ++r) {
          int m = m0 + wm + mi * 16 + ((lane >> 4) << 2) + r;
          dst[(size_t)m * 1024 + n] = acc[mi][ni][r] + bias;
        }
    }
  }
}

// ---------------- flash attention: 4 waves x 16 q-rows, K-tile 64, online softmax ----------------
__global__ __launch_bounds__(256) void attn_kernel(const unsigned short* __restrict__ Qh,
                                                   const unsigned short* __restrict__ Kh,
                                                   const unsigned short* __restrict__ Vt,
                                                   float* __restrict__ AO) {
  __shared__ unsigned short Ks[64 * 64];  // [key][d], 128B rows, XOR-swizzled 16B units
  __shared__ unsigned short Vs[64 * 64];  // [d][key], same swizzle
  __shared__ unsigned short Ps[4 * 16 * 64];  // per-wave P, swizzled

  const int tid = threadIdx.x, lane = tid & 63, wave = tid >> 6;
  const int bh = blockIdx.y;
  const int q0 = blockIdx.x * 64 + wave * 16;

  const size_t qoff = ((size_t)bh * 2048 + q0 + (lane & 15)) * 64 + ((lane >> 4) * 8);
  bf16x8 qa0 = *(const bf16x8*)(Qh + qoff);
  bf16x8 qa1 = *(const bf16x8*)(Qh + qoff + 32);

  f32x4 o[4] = {};
  float mrow[4] = {-__builtin_inff(), -__builtin_inff(), -__builtin_inff(), -__builtin_inff()};
  float lrow[4] = {0.f, 0.f, 0.f, 0.f};

  const unsigned short* Kgb = Kh + (size_t)bh * 131072;
  const unsigned short* Vgb = Vt + (size_t)bh * 131072;

  for (int kt = 0; kt < 32; ++kt) {
    // stage K[64 keys][64 d] and Vt[64 d][64 keys]
#pragma unroll
    for (int x = 0; x < 2; ++x) {
      int q = tid + x * 256;
      int row = q >> 3, u = q & 7;
      u32x4 kv = *(const u32x4*)(Kgb + (size_t)(kt * 64 + row) * 64 + u * 8);
      u32x4 vv = *(const u32x4*)(Vgb + (size_t)row * 2048 + kt * 64 + u * 8);
      int woff = row * 64 + ((u ^ (row & 7)) * 8);
      *(u32x4*)(Ks + woff) = kv;
      *(u32x4*)(Vs + woff) = vv;
    }
    __syncthreads();

    // S = Q K^T (Q pre-scaled by 1/8)
    f32x4 sa[4];
#pragma unroll
    for (int ni = 0; ni < 4; ++ni) {
      int row = ni * 16 + (lane & 15);
      int sw = row & 7;
      bf16x8 k0 = *(const bf16x8*)(Ks + row * 64 + (((lane >> 4) ^ sw) * 8));
      bf16x8 k1 = *(const bf16x8*)(Ks + row * 64 + ((((lane >> 4) + 4) ^ sw) * 8));
      f32x4 z = {0.f, 0.f, 0.f, 0.f};
      z = __builtin_amdgcn_mfma_f32_16x16x32_bf16(qa0, k0, z, 0, 0, 0);
      sa[ni] = __builtin_amdgcn_mfma_f32_16x16x32_bf16(qa1, k1, z, 0, 0, 0);
    }

    // online softmax over this tile's 64 keys
    float pv[4][4];
#pragma unroll
    for (int r = 0; r < 4; ++r) {
      float t = fmaxf(fmaxf(sa[0][r], sa[1][r]), fmaxf(sa[2][r], sa[3][r]));
#pragma unroll
      for (int off = 1; off < 16; off <<= 1) t = fmaxf(t, __shfl_xor(t, off));
      float nm = fmaxf(mrow[r], t);
      float al = __expf(mrow[r] - nm);
      mrow[r] = nm;
      float ssum = 0.f;
#pragma unroll
      for (int ni = 0; ni < 4; ++ni) {
        float p = __expf(sa[ni][r] - nm);
        pv[ni][r] = p;
        ssum += p;
      }
#pragma unroll
      for (int off = 1; off < 16; off <<= 1) ssum += __shfl_xor(ssum, off);
      lrow[r] = lrow[r] * al + ssum;
#pragma unroll
      for (int di = 0; di < 4; ++di) o[di][r] *= al;
    }

    // P -> LDS (per-wave region, swizzled rows)
#pragma unroll
    for (int ni = 0; ni < 4; ++ni)
#pragma unroll
      for (int r = 0; r < 4; ++r) {
        int prow = ((lane >> 4) << 2) + r;
        int pcol = ni * 16 + (lane & 15);
        Ps[wave * 1024 + prow * 64 + (pcol ^ ((prow & 7) << 3))] = f2bf(pv[ni][r]);
      }

    // O += P V  (A=P from LDS, B=V^T rows)
    {
      int prow = lane & 15;
      int psw = prow & 7;
      bf16x8 pa0 = *(const bf16x8*)(Ps + wave * 1024 + prow * 64 + (((lane >> 4) ^ psw) * 8));
      bf16x8 pa1 = *(const bf16x8*)(Ps + wave * 1024 + prow * 64 + ((((lane >> 4) + 4) ^ psw) * 8));
#pragma unroll
      for (int di = 0; di < 4; ++di) {
        int vrow = di * 16 + (lane & 15);
        int vsw = vrow & 7;
        bf16x8 vb0 = *(const bf16x8*)(Vs + vrow * 64 + (((lane >> 4) ^ vsw) * 8));
        bf16x8 vb1 = *(const bf16x8*)(Vs + vrow * 64 + ((((lane >> 4) + 4) ^ vsw) * 8));
        o[di] = __builtin_amdgcn_mfma_f32_16x16x32_bf16(pa0, vb0, o[di], 0, 0, 0);
        o[di] = __builtin_amdgcn_mfma_f32_16x16x32_bf16(pa1, vb1, o[di], 0, 0, 0);
      }
    }
    __syncthreads();
  }

  const int b = bh >> 4, h = bh & 15;
  float il[4];
#pragma unroll
  for (int r = 0; r < 4; ++r) il[r] = 1.0f / lrow[r];
#pragma unroll
  for (int di = 0; di < 4; ++di)
#pragma unroll
    for (int r = 0; r < 4; ++r) {
      int s = q0 + ((lane >> 4) << 2) + r;
      int dcol = h * 64 + di * 16 + (lane & 15);
      AO[(size_t)(b * 2048 + s) * 1024 + dcol] = o[di][r] * il[r];
    }
}

extern "C" void kernel_launch(void* const* d_in, const int* in_sizes, int n_in,
                              void* d_out, int out_size, void* d_ws, size_t ws_size,
                              hipStream_t stream) {
  const float* query = (const float*)d_in[0];
  const float* key = (const float*)d_in[1];
  const float* value = (const float*)d_in[2];
  const float* Wq = (const float*)d_in[3];
  const float* Wk = (const float*)d_in[4];
  const float* Wv = (const float*)d_in[5];
  const float* Wo = (const float*)d_in[6];
  const float* bo = (const float*)d_in[7];

  char* ws = (char*)d_ws;
  unsigned short* Wb = (unsigned short*)(ws + WS_WB);
  float* cosT = (float*)(ws + WS_COS);
  float* sinT = (float*)(ws + WS_SIN);
  unsigned short* Qh = (unsigned short*)(ws + WS_QH);
  unsigned short* Kh = (unsigned short*)(ws + WS_KH);
  unsigned short* Vt = (unsigned short*)(ws + WS_VT);
  float* AO = (float*)(ws + WS_AO);

  cvt_w<<<dim3(1024, 4), 256, 0, stream>>>(Wq, Wk, Wv, Wo, Wb);
  rope_tab<<<256, 256, 0, stream>>>(cosT, sinT);
  gemm_mha<0><<<dim3(8, 64), 256, 0, stream>>>(query, Wb, Qh, cosT, sinT, nullptr);
  gemm_mha<1><<<dim3(8, 64), 256, 0, stream>>>(key, Wb + 1048576, Kh, cosT, sinT, nullptr);
  gemm_mha<2><<<dim3(8, 64), 256, 0, stream>>>(value, Wb + 2097152, Vt, cosT, sinT, nullptr);
  attn_kernel<<<dim3(32, 64), 256, 0, stream>>>(Qh, Kh, Vt, AO);
  gemm_mha<3><<<dim3(8, 64), 256, 0, stream>>>(AO, Wb + 3145728, d_out, cosT, sinT, bo);
}